// Round 1
// baseline (1346.659 us; speedup 1.0000x reference)
//
#include <hip/hip_runtime.h>
#include <hip/hip_bf16.h>

// SpatialAttentionLayer: T=120 B=64 N=20 D=256 H=8 F=32
// v1: f32 vector GEMMs (no MFMA yet) + fused attention.
//   kernel 1: KV projection GEMM  X(153600x256) @ [Wk|Wv]^T -> K,V (bf16 in ws)
//   kernel 2: Q projection GEMMs (grid.z = joint) -> Q (bf16 in ws)
//   kernel 3: per-(t,b) attention over all heads/joints -> out (f32)
// ws usage: K 78.6MB + V 78.6MB + Q 78.6MB = 236MB bf16.

constexpr int T_ = 120, B_ = 64, N_ = 20, D_ = 256, H_ = 8, F_ = 32;
constexpr int TB_ = T_ * B_;          // 7680
constexpr int MKV = TB_ * N_;         // 153600 rows of x
constexpr float SCALE = 0.17677669529663687f;  // 1/sqrt(F)

#define BM 64
#define BN 64
#define BK 64

__device__ __forceinline__ unsigned short f2bf(float f) {
  unsigned int u = __float_as_uint(f);
  unsigned int r = (u + 0x7fffu + ((u >> 16) & 1u)) >> 16;
  return (unsigned short)r;
}
__device__ __forceinline__ float bf2f(unsigned short s) {
  return __uint_as_float(((unsigned int)s) << 16);
}

// ---------------- Kernel 1: K/V projection GEMM ----------------
// grid (MKV/BM=2400, 512/BN=8), block 256
__global__ __launch_bounds__(256) void kv_gemm(
    const float* __restrict__ X, const float* __restrict__ Wk,
    const float* __restrict__ bk, const float* __restrict__ Wv,
    const float* __restrict__ bv, unsigned short* __restrict__ Kb,
    unsigned short* __restrict__ Vb) {
  __shared__ float Xs[BK][BM + 4];
  __shared__ float Ws[BK][BN + 4];
  const int tid = threadIdx.x;
  const int rb = blockIdx.x * BM;
  const int cb_all = blockIdx.y * BN;  // 0..511
  const bool isV = cb_all >= 256;
  const float* __restrict__ W = isV ? Wv : Wk;
  const float* __restrict__ bias = isV ? bv : bk;
  unsigned short* __restrict__ Out = isV ? Vb : Kb;
  const int cb = cb_all & 255;

  const int tx = tid & 15, ty = tid >> 4;
  const int lr = tid >> 4;          // row group 0..15
  const int lc = (tid & 15) * 4;    // k offset within tile

  float acc[4][4] = {};

  for (int k0 = 0; k0 < D_; k0 += BK) {
#pragma unroll
    for (int j = 0; j < 4; ++j) {
      int r = lr + j * 16;
      float4 xv = *(const float4*)&X[(size_t)(rb + r) * D_ + k0 + lc];
      Xs[lc + 0][r] = xv.x; Xs[lc + 1][r] = xv.y;
      Xs[lc + 2][r] = xv.z; Xs[lc + 3][r] = xv.w;
      float4 wv = *(const float4*)&W[(size_t)(cb + r) * D_ + k0 + lc];
      Ws[lc + 0][r] = wv.x; Ws[lc + 1][r] = wv.y;
      Ws[lc + 2][r] = wv.z; Ws[lc + 3][r] = wv.w;
    }
    __syncthreads();
#pragma unroll 16
    for (int k = 0; k < BK; ++k) {
      float4 a = *(const float4*)(&Xs[k][ty * 4]);
      float4 b = *(const float4*)(&Ws[k][tx * 4]);
      float av[4] = {a.x, a.y, a.z, a.w};
      float bv2[4] = {b.x, b.y, b.z, b.w};
#pragma unroll
      for (int i = 0; i < 4; ++i)
#pragma unroll
        for (int j = 0; j < 4; ++j) acc[i][j] = fmaf(av[i], bv2[j], acc[i][j]);
    }
    __syncthreads();
  }

  const int cg = cb + tx * 4;
#pragma unroll
  for (int i = 0; i < 4; ++i) {
    size_t m = (size_t)(rb + ty * 4 + i);
    ushort4 pk;
    pk.x = f2bf(acc[i][0] + bias[cg + 0]);
    pk.y = f2bf(acc[i][1] + bias[cg + 1]);
    pk.z = f2bf(acc[i][2] + bias[cg + 2]);
    pk.w = f2bf(acc[i][3] + bias[cg + 3]);
    *(ushort4*)&Out[m * 256 + cg] = pk;
  }
}

// ---------------- Kernel 2: Q projection GEMM (per joint) ----------------
// grid (TB/BM=120, 256/BN=4, N=20), block 256
__global__ __launch_bounds__(256) void q_gemm(
    const float* __restrict__ X, const float* __restrict__ Wq,
    const float* __restrict__ bq, unsigned short* __restrict__ Qb) {
  __shared__ float Xs[BK][BM + 4];
  __shared__ float Ws[BK][BN + 4];
  const int tid = threadIdx.x;
  const int n = blockIdx.z;
  const int rb = blockIdx.x * BM;   // over TB
  const int cb = blockIdx.y * BN;   // over 256 (= h*F+f)

  const int tx = tid & 15, ty = tid >> 4;
  const int lr = tid >> 4;
  const int lc = (tid & 15) * 4;

  float acc[4][4] = {};

  for (int k0 = 0; k0 < D_; k0 += BK) {
#pragma unroll
    for (int j = 0; j < 4; ++j) {
      int r = lr + j * 16;
      int tb = rb + r;
      float4 xv = *(const float4*)&X[((size_t)tb * N_ + n) * D_ + k0 + lc];
      Xs[lc + 0][r] = xv.x; Xs[lc + 1][r] = xv.y;
      Xs[lc + 2][r] = xv.z; Xs[lc + 3][r] = xv.w;
      int c = cb + r;
      int wrow = ((c >> 5) * N_ + n) * F_ + (c & 31);
      float4 wv = *(const float4*)&Wq[(size_t)wrow * D_ + k0 + lc];
      Ws[lc + 0][r] = wv.x; Ws[lc + 1][r] = wv.y;
      Ws[lc + 2][r] = wv.z; Ws[lc + 3][r] = wv.w;
    }
    __syncthreads();
#pragma unroll 16
    for (int k = 0; k < BK; ++k) {
      float4 a = *(const float4*)(&Xs[k][ty * 4]);
      float4 b = *(const float4*)(&Ws[k][tx * 4]);
      float av[4] = {a.x, a.y, a.z, a.w};
      float bv2[4] = {b.x, b.y, b.z, b.w};
#pragma unroll
      for (int i = 0; i < 4; ++i)
#pragma unroll
        for (int j = 0; j < 4; ++j) acc[i][j] = fmaf(av[i], bv2[j], acc[i][j]);
    }
    __syncthreads();
  }

  const int cg = cb + tx * 4;
#pragma unroll
  for (int i = 0; i < 4; ++i) {
    int tb = rb + ty * 4 + i;
#pragma unroll
    for (int j = 0; j < 4; ++j) {
      int c = cg + j;
      int brow = ((c >> 5) * N_ + n) * F_ + (c & 31);
      acc[i][j] += bq[brow];
    }
    ushort4 pk;
    pk.x = f2bf(acc[i][0]); pk.y = f2bf(acc[i][1]);
    pk.z = f2bf(acc[i][2]); pk.w = f2bf(acc[i][3]);
    *(ushort4*)&Qb[((size_t)tb * N_ + n) * 256 + cg] = pk;
  }
}

// ---------------- Kernel 3: attention per (t,b) ----------------
// grid 7680, block 256. LDS: 3 * 8*20*33*4B = 63,360B -> 2 blocks/CU.
__global__ __launch_bounds__(256) void attn_kernel(
    const unsigned short* __restrict__ Qb, const unsigned short* __restrict__ Kb,
    const unsigned short* __restrict__ Vb, float* __restrict__ out) {
  __shared__ float Qs[H_][N_][F_ + 1];
  __shared__ float Ks[H_][N_][F_ + 1];
  __shared__ float Vs[H_][N_][F_ + 1];
  const int tb = blockIdx.x;
  const int tid = threadIdx.x;

  // stage Q/K/V for this (t,b): 20 rows x 256 cols each, bf16 -> f32 LDS
  for (int it = tid; it < 1280; it += 256) {
    int r = it >> 6;           // joint row 0..19
    int c4 = (it & 63) * 4;    // col 0,4,...,252
    int h = c4 >> 5, f = c4 & 31;
    size_t base = ((size_t)tb * N_ + r) * D_ + c4;
    ushort4 q = *(const ushort4*)&Qb[base];
    Qs[h][r][f + 0] = bf2f(q.x); Qs[h][r][f + 1] = bf2f(q.y);
    Qs[h][r][f + 2] = bf2f(q.z); Qs[h][r][f + 3] = bf2f(q.w);
    ushort4 k = *(const ushort4*)&Kb[base];
    Ks[h][r][f + 0] = bf2f(k.x); Ks[h][r][f + 1] = bf2f(k.y);
    Ks[h][r][f + 2] = bf2f(k.z); Ks[h][r][f + 3] = bf2f(k.w);
    ushort4 v = *(const ushort4*)&Vb[base];
    Vs[h][r][f + 0] = bf2f(v.x); Vs[h][r][f + 1] = bf2f(v.y);
    Vs[h][r][f + 2] = bf2f(v.z); Vs[h][r][f + 3] = bf2f(v.w);
  }
  __syncthreads();

  if (tid < H_ * N_) {
    const int h = tid / N_;
    const int nn = tid - h * N_;
    float q[F_];
#pragma unroll
    for (int f = 0; f < F_; ++f) q[f] = Qs[h][nn][f];

    float lg[N_];
    float mx = -3.4e38f;
#pragma unroll
    for (int m = 0; m < N_; ++m) {
      float d = 0.f;
#pragma unroll
      for (int f = 0; f < F_; ++f) d = fmaf(q[f], Ks[h][m][f], d);
      d *= SCALE;
      lg[m] = d;
      mx = fmaxf(mx, d);
    }
    float s = 0.f;
#pragma unroll
    for (int m = 0; m < N_; ++m) {
      float e = __expf(lg[m] - mx);
      lg[m] = e;
      s += e;
    }
    float inv = 1.0f / s;
    float o[F_] = {};
#pragma unroll
    for (int m = 0; m < N_; ++m) {
      float p = lg[m] * inv;
#pragma unroll
      for (int f = 0; f < F_; ++f) o[f] = fmaf(p, Vs[h][m][f], o[f]);
    }
    size_t base = ((size_t)tb * N_ + nn) * D_ + h * F_;
#pragma unroll
    for (int f0 = 0; f0 < F_; f0 += 4) {
      float4 v4 = make_float4(o[f0], o[f0 + 1], o[f0 + 2], o[f0 + 3]);
      *(float4*)&out[base + f0] = v4;
    }
  }
}

extern "C" void kernel_launch(void* const* d_in, const int* in_sizes, int n_in,
                              void* d_out, int out_size, void* d_ws, size_t ws_size,
                              hipStream_t stream) {
  const float* inputs = (const float*)d_in[0];
  const float* Wk = (const float*)d_in[1];
  const float* bk = (const float*)d_in[2];
  const float* Wv = (const float*)d_in[3];
  const float* bv = (const float*)d_in[4];
  const float* Wq = (const float*)d_in[5];
  const float* bq = (const float*)d_in[6];
  float* out = (float*)d_out;

  // ws carve: K, V, Q bf16 buffers, each MKV*256*2 = 78,643,200 bytes
  const size_t seg = (size_t)MKV * 256 * sizeof(unsigned short);
  unsigned short* Kb = (unsigned short*)d_ws;
  unsigned short* Vb = (unsigned short*)((char*)d_ws + seg);
  unsigned short* Qb = (unsigned short*)((char*)d_ws + 2 * seg);

  kv_gemm<<<dim3(MKV / BM, 512 / BN), 256, 0, stream>>>(inputs, Wk, bk, Wv, bv, Kb, Vb);
  q_gemm<<<dim3(TB_ / BM, 256 / BN, N_), 256, 0, stream>>>(inputs, Wq, bq, Qb);
  attn_kernel<<<TB_, 256, 0, stream>>>(Qb, Kb, Vb, out);
}

// Round 3
// 716.004 us; speedup vs baseline: 1.8808x; 1.8808x over previous
//
#include <hip/hip_runtime.h>
#include <hip/hip_bf16.h>

// SpatialAttentionLayer: T=120 B=64 N=20 D=256 H=8 F=32
// v3: v2 with the attn staging bug fixed (K/V chunk split was at 2048, must be 1280;
//     V rows 8-19 were never staged and K staging overflowed into Vs).
//   kernel 1: KV projection  X(153600x256) @ [Wk|Wv]^T -> K,V bf16  (MFMA)
//   kernel 2: Q projection (per joint)                  -> Q bf16   (MFMA)
//   kernel 3: per-(t,b) attention (f32 K/V in LDS, Q in regs)       -> out f32
// ws: Kb 78.6MB + Vb 78.6MB + Qb 78.6MB = 236MB.

constexpr int T_ = 120, B_ = 64, N_ = 20, D_ = 256, H_ = 8, F_ = 32;
constexpr int TB_ = T_ * B_;          // 7680
constexpr int MKV = TB_ * N_;         // 153600
constexpr float SCALE = 0.17677669529663687f;  // 1/sqrt(F)

typedef short bf16x8 __attribute__((ext_vector_type(8)));
typedef short s16x4 __attribute__((ext_vector_type(4)));
typedef float f32x4 __attribute__((ext_vector_type(4)));

__device__ __forceinline__ unsigned short f2bf(float f) {
  unsigned int u = __float_as_uint(f);
  return (unsigned short)((u + 0x7fffu + ((u >> 16) & 1u)) >> 16);
}
__device__ __forceinline__ float bf2f(unsigned short s) {
  return __uint_as_float(((unsigned int)s) << 16);
}

// LDS tile: 128 rows x 64 k of bf16, row stride 72 shorts (144B) ->
// row bank-start rotates by 4 banks/row: >=2-way-max b128 reads (free, m136).
#define LDSTRIDE 72

// ---------------- Kernel 1: K/V projection (MFMA) ----------------
// grid (4, 1200): x = col-tile over 512 (K|V), y = row-tile over MKV. block 256.
__global__ __launch_bounds__(256, 2) void kv_gemm(
    const float* __restrict__ X, const float* __restrict__ Wk,
    const float* __restrict__ bk, const float* __restrict__ Wv,
    const float* __restrict__ bv, unsigned short* __restrict__ Kb,
    unsigned short* __restrict__ Vb) {
  __shared__ unsigned short As[128 * LDSTRIDE];
  __shared__ unsigned short Bs[128 * LDSTRIDE];
  const int tid = threadIdx.x;
  const int lane = tid & 63;
  const int wave = tid >> 6;
  const int wm = wave >> 1, wn = wave & 1;
  const int cbAll = blockIdx.x * 128;      // 0,128,256,384
  const int rb = blockIdx.y * 128;
  const bool isV = cbAll >= 256;
  const float* __restrict__ W = isV ? Wv : Wk;
  const float* __restrict__ bias = isV ? bv : bk;
  unsigned short* __restrict__ Out = isV ? Vb : Kb;
  const int w0 = cbAll & 255;

  const int sr = tid >> 4;          // staging row subgroup 0..15
  const int sk = (tid & 15) * 4;    // staging k offset (elements)

  f32x4 acc[4][4];
#pragma unroll
  for (int i = 0; i < 4; ++i)
#pragma unroll
    for (int j = 0; j < 4; ++j) acc[i][j] = {0.f, 0.f, 0.f, 0.f};

  for (int k0 = 0; k0 < 256; k0 += 64) {
    __syncthreads();
#pragma unroll
    for (int i = 0; i < 8; ++i) {
      const int m = i * 16 + sr;
      float4 xv = *(const float4*)&X[(size_t)(rb + m) * 256 + k0 + sk];
      s16x4 pa = {(short)f2bf(xv.x), (short)f2bf(xv.y), (short)f2bf(xv.z), (short)f2bf(xv.w)};
      *(s16x4*)&As[m * LDSTRIDE + sk] = pa;
      float4 wv = *(const float4*)&W[(size_t)(w0 + m) * 256 + k0 + sk];
      s16x4 pb = {(short)f2bf(wv.x), (short)f2bf(wv.y), (short)f2bf(wv.z), (short)f2bf(wv.w)};
      *(s16x4*)&Bs[m * LDSTRIDE + sk] = pb;
    }
    __syncthreads();
#pragma unroll
    for (int kk = 0; kk < 64; kk += 32) {
      bf16x8 a[4], b[4];
#pragma unroll
      for (int mi = 0; mi < 4; ++mi) {
        int r = wm * 64 + mi * 16 + (lane & 15);
        a[mi] = *(const bf16x8*)&As[r * LDSTRIDE + kk + (lane >> 4) * 8];
      }
#pragma unroll
      for (int ni = 0; ni < 4; ++ni) {
        int r = wn * 64 + ni * 16 + (lane & 15);
        b[ni] = *(const bf16x8*)&Bs[r * LDSTRIDE + kk + (lane >> 4) * 8];
      }
#pragma unroll
      for (int mi = 0; mi < 4; ++mi)
#pragma unroll
        for (int ni = 0; ni < 4; ++ni)
          acc[mi][ni] = __builtin_amdgcn_mfma_f32_16x16x32_bf16(a[mi], b[ni], acc[mi][ni], 0, 0, 0);
    }
  }

  const int lc = lane & 15, lg4 = (lane >> 4) * 4;
#pragma unroll
  for (int mi = 0; mi < 4; ++mi) {
#pragma unroll
    for (int ni = 0; ni < 4; ++ni) {
      const int c = w0 + wn * 64 + ni * 16 + lc;
      const float bb = bias[c];
#pragma unroll
      for (int i = 0; i < 4; ++i) {
        const int row = rb + wm * 64 + mi * 16 + lg4 + i;
        Out[(size_t)row * 256 + c] = f2bf(acc[mi][ni][i] + bb);
      }
    }
  }
}

// ---------------- Kernel 2: Q projection per joint (MFMA) ----------------
// grid (2, 60, 20): x = col-tile over 256, y = row-tile over TB, z = joint.
__global__ __launch_bounds__(256, 2) void q_gemm(
    const float* __restrict__ X, const float* __restrict__ Wq,
    const float* __restrict__ bq, unsigned short* __restrict__ Qb) {
  __shared__ unsigned short As[128 * LDSTRIDE];
  __shared__ unsigned short Bs[128 * LDSTRIDE];
  const int tid = threadIdx.x;
  const int lane = tid & 63;
  const int wave = tid >> 6;
  const int wm = wave >> 1, wn = wave & 1;
  const int cb = blockIdx.x * 128;
  const int rb = blockIdx.y * 128;   // over TB
  const int n = blockIdx.z;

  const int sr = tid >> 4;
  const int sk = (tid & 15) * 4;

  f32x4 acc[4][4];
#pragma unroll
  for (int i = 0; i < 4; ++i)
#pragma unroll
    for (int j = 0; j < 4; ++j) acc[i][j] = {0.f, 0.f, 0.f, 0.f};

  for (int k0 = 0; k0 < 256; k0 += 64) {
    __syncthreads();
#pragma unroll
    for (int i = 0; i < 8; ++i) {
      const int m = i * 16 + sr;
      float4 xv = *(const float4*)&X[((size_t)(rb + m) * 20 + n) * 256 + k0 + sk];
      s16x4 pa = {(short)f2bf(xv.x), (short)f2bf(xv.y), (short)f2bf(xv.z), (short)f2bf(xv.w)};
      *(s16x4*)&As[m * LDSTRIDE + sk] = pa;
      const int c = cb + m;
      const int wrow = (c >> 5) * 640 + n * 32 + (c & 31);
      float4 wv = *(const float4*)&Wq[(size_t)wrow * 256 + k0 + sk];
      s16x4 pb = {(short)f2bf(wv.x), (short)f2bf(wv.y), (short)f2bf(wv.z), (short)f2bf(wv.w)};
      *(s16x4*)&Bs[m * LDSTRIDE + sk] = pb;
    }
    __syncthreads();
#pragma unroll
    for (int kk = 0; kk < 64; kk += 32) {
      bf16x8 a[4], b[4];
#pragma unroll
      for (int mi = 0; mi < 4; ++mi) {
        int r = wm * 64 + mi * 16 + (lane & 15);
        a[mi] = *(const bf16x8*)&As[r * LDSTRIDE + kk + (lane >> 4) * 8];
      }
#pragma unroll
      for (int ni = 0; ni < 4; ++ni) {
        int r = wn * 64 + ni * 16 + (lane & 15);
        b[ni] = *(const bf16x8*)&Bs[r * LDSTRIDE + kk + (lane >> 4) * 8];
      }
#pragma unroll
      for (int mi = 0; mi < 4; ++mi)
#pragma unroll
        for (int ni = 0; ni < 4; ++ni)
          acc[mi][ni] = __builtin_amdgcn_mfma_f32_16x16x32_bf16(a[mi], b[ni], acc[mi][ni], 0, 0, 0);
    }
  }

  const int lc = lane & 15, lg4 = (lane >> 4) * 4;
#pragma unroll
  for (int mi = 0; mi < 4; ++mi) {
#pragma unroll
    for (int ni = 0; ni < 4; ++ni) {
      const int c = cb + wn * 64 + ni * 16 + lc;
      const float bb = bq[(c >> 5) * 640 + n * 32 + (c & 31)];
#pragma unroll
      for (int i = 0; i < 4; ++i) {
        const int row = rb + wm * 64 + mi * 16 + lg4 + i;
        Qb[((size_t)row * 20 + n) * 256 + c] = f2bf(acc[mi][ni][i] + bb);
      }
    }
  }
}

// ---------------- Kernel 3: attention per (t,b) ----------------
// grid 7680, block 192 (3 waves; 160 compute threads).
// K/V staged as f32 in LDS; h-stride 724 floats => the 8 h-groups hit banks
// 0,20,8,28,16,4,24,12 (724%32=20, all distinct); same-h lanes broadcast.
constexpr int HS = 724;
__global__ __launch_bounds__(192) void attn_kernel(
    const unsigned short* __restrict__ Qb, const unsigned short* __restrict__ Kb,
    const unsigned short* __restrict__ Vb, float* __restrict__ out) {
  __shared__ float Ks[8 * HS];
  __shared__ float Vs[8 * HS];
  const int tb = blockIdx.x;
  const int tid = threadIdx.x;

  // stage K,V: 20 rows x 64 ushort4-quads each; one loop stages BOTH arrays
  // at the same (row,h,f4) -> 1280 iterations total. (v2 bug: split at 2048.)
  for (int c = tid; c < 1280; c += 192) {
    const int row = c >> 6;        // n: 0..19
    const int quad = c & 63;
    const int h = quad >> 3, f4 = (quad & 7) * 4;
    const size_t base = ((size_t)tb * 20 + row) * 256 + h * 32 + f4;
    const int didx = h * HS + row * 36 + f4;
    ushort4 uk = *(const ushort4*)&Kb[base];
    float4 fk;
    fk.x = bf2f(uk.x); fk.y = bf2f(uk.y); fk.z = bf2f(uk.z); fk.w = bf2f(uk.w);
    *(float4*)&Ks[didx] = fk;
    ushort4 uv = *(const ushort4*)&Vb[base];
    float4 fv;
    fv.x = bf2f(uv.x); fv.y = bf2f(uv.y); fv.z = bf2f(uv.z); fv.w = bf2f(uv.w);
    *(float4*)&Vs[didx] = fv;
  }
  __syncthreads();

  if (tid < 160) {
    const int h = tid / 20;
    const int nn = tid - h * 20;
    float q[32];
    const unsigned short* __restrict__ qp = &Qb[((size_t)tb * 20 + nn) * 256 + h * 32];
#pragma unroll
    for (int j = 0; j < 8; ++j) {
      ushort4 u = *(const ushort4*)&qp[j * 4];
      q[j * 4 + 0] = bf2f(u.x); q[j * 4 + 1] = bf2f(u.y);
      q[j * 4 + 2] = bf2f(u.z); q[j * 4 + 3] = bf2f(u.w);
    }
    float lg[20];
    float mx = -3.4e38f;
#pragma unroll
    for (int m = 0; m < 20; ++m) {
      float d = 0.f;
#pragma unroll
      for (int f = 0; f < 32; ++f) d = fmaf(q[f], Ks[h * HS + m * 36 + f], d);
      d *= SCALE;
      lg[m] = d;
      mx = fmaxf(mx, d);
    }
    float s = 0.f;
#pragma unroll
    for (int m = 0; m < 20; ++m) {
      float e = __expf(lg[m] - mx);
      lg[m] = e;
      s += e;
    }
    const float inv = 1.0f / s;
    float o[32] = {};
#pragma unroll
    for (int m = 0; m < 20; ++m) {
      const float p = lg[m] * inv;
#pragma unroll
      for (int f = 0; f < 32; ++f) o[f] = fmaf(p, Vs[h * HS + m * 36 + f], o[f]);
    }
    const size_t base = ((size_t)tb * 20 + nn) * 256 + h * 32;
#pragma unroll
    for (int f0 = 0; f0 < 32; f0 += 4) {
      float4 v4 = make_float4(o[f0], o[f0 + 1], o[f0 + 2], o[f0 + 3]);
      *(float4*)&out[base + f0] = v4;
    }
  }
}

extern "C" void kernel_launch(void* const* d_in, const int* in_sizes, int n_in,
                              void* d_out, int out_size, void* d_ws, size_t ws_size,
                              hipStream_t stream) {
  const float* inputs = (const float*)d_in[0];
  const float* Wk = (const float*)d_in[1];
  const float* bk = (const float*)d_in[2];
  const float* Wv = (const float*)d_in[3];
  const float* bv = (const float*)d_in[4];
  const float* Wq = (const float*)d_in[5];
  const float* bq = (const float*)d_in[6];
  float* out = (float*)d_out;

  const size_t seg = (size_t)MKV * 256 * sizeof(unsigned short);  // 78.6 MB
  unsigned short* Kb = (unsigned short*)d_ws;
  unsigned short* Vb = (unsigned short*)((char*)d_ws + seg);
  unsigned short* Qb = (unsigned short*)((char*)d_ws + 2 * seg);

  kv_gemm<<<dim3(4, 1200), 256, 0, stream>>>(inputs, Wk, bk, Wv, bv, Kb, Vb);
  q_gemm<<<dim3(2, 60, 20), 256, 0, stream>>>(inputs, Wq, bq, Qb);
  attn_kernel<<<TB_, 192, 0, stream>>>(Qb, Kb, Vb, out);
}

// Round 5
// 567.144 us; speedup vs baseline: 2.3745x; 1.2625x over previous
//
#include <hip/hip_runtime.h>
#include <hip/hip_bf16.h>

// SpatialAttentionLayer: T=120 B=64 N=20 D=256 H=8 F=32
// v4b: resubmit of v4 (round-4 bench never ran: GPU acquisition timeout).
//   kernel 0: prep — Wcat[n][768][256] bf16 = [Wk|Wv|Wq_n], bcat f32
//   kernel 1: fused projection GEMM (X read ONCE) -> K,V bf16 in ws; Q f32 in d_out
//   kernel 2: per-(t,b) attention, reads Q from d_out in-place, writes output
// Changes vs v4: dropped __restrict__ on attn Qf/out (they alias d_out).
// ws: Kb 78.6MB + Vb 78.6MB + Wcat 7.86MB + bcat 61KB = 165.3 MB.

constexpr int T_ = 120, B_ = 64, N_ = 20, D_ = 256, H_ = 8, F_ = 32;
constexpr int TB_ = T_ * B_;          // 7680
constexpr int MKV = TB_ * N_;         // 153600
constexpr float SCALE = 0.17677669529663687f;  // 1/sqrt(F)
constexpr int COLS = 768;             // K(256) | V(256) | Q(256)

typedef short bf16x8 __attribute__((ext_vector_type(8)));
typedef short s16x4 __attribute__((ext_vector_type(4)));
typedef float f32x4 __attribute__((ext_vector_type(4)));

__device__ __forceinline__ unsigned short f2bf(float f) {
  unsigned int u = __float_as_uint(f);
  return (unsigned short)((u + 0x7fffu + ((u >> 16) & 1u)) >> 16);
}
__device__ __forceinline__ float bf2f(unsigned short s) {
  return __uint_as_float(((unsigned int)s) << 16);
}

// ---------------- Kernel 0: weight concat + bf16 convert ----------------
__global__ __launch_bounds__(256) void prep(
    const float* __restrict__ Wk, const float* __restrict__ bk,
    const float* __restrict__ Wv, const float* __restrict__ bv,
    const float* __restrict__ Wq, const float* __restrict__ bq,
    unsigned short* __restrict__ Wcat, float* __restrict__ bcat) {
  const int g = blockIdx.x * 256 + threadIdx.x;
  const int WCH = 20 * COLS * 64;  // chunks of 4 elems
  if (g < WCH) {
    const int row = g >> 6;
    const int k4 = (g & 63) * 4;
    const int n = row / COLS, c = row - n * COLS;
    const float* src;
    if (c < 256) src = &Wk[(size_t)c * 256];
    else if (c < 512) src = &Wv[(size_t)(c - 256) * 256];
    else { int h = (c - 512) >> 5, f = (c - 512) & 31; src = &Wq[(size_t)((h * 20 + n) * 32 + f) * 256]; }
    float4 v = *(const float4*)&src[k4];
    s16x4 p = {(short)f2bf(v.x), (short)f2bf(v.y), (short)f2bf(v.z), (short)f2bf(v.w)};
    *(s16x4*)&Wcat[(size_t)row * 256 + k4] = p;
  } else {
    const int idx = g - WCH;
    if (idx < 20 * COLS) {
      const int n = idx / COLS, c = idx - n * COLS;
      float b;
      if (c < 256) b = bk[c];
      else if (c < 512) b = bv[c - 256];
      else { int h = (c - 512) >> 5, f = (c - 512) & 31; b = bq[(h * 20 + n) * 32 + f]; }
      bcat[idx] = b;
    }
  }
}

// ---------------- Kernel 1: fused projection GEMM ----------------
// 7200 blocks (XCD-swizzled), 256 threads. Tile 128 rows x 128 cols, BK=64.
// LDS 2x16KB, XOR chunk swizzle (c ^= m&7) applied on BOTH write and read.
__global__ __launch_bounds__(256, 2) void fused_gemm(
    const float* __restrict__ X, const unsigned short* __restrict__ Wcat,
    const float* __restrict__ bcat, unsigned short* __restrict__ Kb,
    unsigned short* __restrict__ Vb, float* __restrict__ Qout) {
  __shared__ unsigned short As[128 * 64];
  __shared__ unsigned short Bs[128 * 64];
  const int bidx = blockIdx.x;
  const int w = (bidx & 7) * 900 + (bidx >> 3);   // T1: 7200 = 8*900, bijective
  const int x = w % 6;
  const int y = (w / 6) % 60;
  const int n = w / 360;
  const int cb = x * 128;      // 0..640 within [K|V|Q]
  const int rb = y * 128;      // tb base
  const int tid = threadIdx.x, lane = tid & 63, wave = tid >> 6;
  const int wm = wave >> 1, wn = wave & 1;

  f32x4 acc[4][4];
#pragma unroll
  for (int i = 0; i < 4; ++i)
#pragma unroll
    for (int j = 0; j < 4; ++j) acc[i][j] = {0.f, 0.f, 0.f, 0.f};

  float4 ar[4][2];
  bf16x8 br[4];

  auto loadA = [&](int k0) {
#pragma unroll
    for (int i = 0; i < 4; ++i) {
      const int q = i * 256 + tid;
      const int m = q >> 3, c = q & 7;
      const float* s = &X[((size_t)(rb + m) * 20 + n) * 256 + k0 + c * 8];
      ar[i][0] = *(const float4*)s;
      ar[i][1] = *(const float4*)(s + 4);
    }
  };
  auto loadB = [&](int k0) {
#pragma unroll
    for (int i = 0; i < 4; ++i) {
      const int q = i * 256 + tid;
      const int m = q >> 3, c = q & 7;
      br[i] = *(const bf16x8*)&Wcat[((size_t)(n * COLS + cb + m)) * 256 + k0 + c * 8];
    }
  };

  loadA(0);
  loadB(0);

  for (int k = 0; k < 4; ++k) {
    if (k) __syncthreads();
#pragma unroll
    for (int i = 0; i < 4; ++i) {
      const int q = i * 256 + tid;
      const int m = q >> 3, c = q & 7;
      const int sw = m * 64 + ((c ^ (m & 7)) << 3);
      bf16x8 pa = {(short)f2bf(ar[i][0].x), (short)f2bf(ar[i][0].y),
                   (short)f2bf(ar[i][0].z), (short)f2bf(ar[i][0].w),
                   (short)f2bf(ar[i][1].x), (short)f2bf(ar[i][1].y),
                   (short)f2bf(ar[i][1].z), (short)f2bf(ar[i][1].w)};
      *(bf16x8*)&As[sw] = pa;
      *(bf16x8*)&Bs[sw] = br[i];
    }
    __syncthreads();
    if (k < 3) {               // prefetch next k-step while computing this one
      loadA((k + 1) * 64);
      loadB((k + 1) * 64);
    }
#pragma unroll
    for (int kk = 0; kk < 64; kk += 32) {
      const int cc = (kk >> 3) + (lane >> 4);
      bf16x8 a[4], b[4];
#pragma unroll
      for (int mi = 0; mi < 4; ++mi) {
        const int r = wm * 64 + mi * 16 + (lane & 15);
        a[mi] = *(const bf16x8*)&As[r * 64 + ((cc ^ (r & 7)) << 3)];
      }
#pragma unroll
      for (int ni = 0; ni < 4; ++ni) {
        const int r = wn * 64 + ni * 16 + (lane & 15);
        b[ni] = *(const bf16x8*)&Bs[r * 64 + ((cc ^ (r & 7)) << 3)];
      }
#pragma unroll
      for (int mi = 0; mi < 4; ++mi)
#pragma unroll
        for (int ni = 0; ni < 4; ++ni)
          acc[mi][ni] = __builtin_amdgcn_mfma_f32_16x16x32_bf16(a[mi], b[ni], acc[mi][ni], 0, 0, 0);
    }
  }

  // epilogue: cb decides destination (whole 128-col tile is inside one of K/V/Q)
  const int lc = lane & 15, lg4 = (lane >> 4) * 4;
  const bool isQ = cb >= 512;
  unsigned short* __restrict__ dst16 = (cb < 256) ? Kb : Vb;
  const int c0 = cb & 255;
#pragma unroll
  for (int mi = 0; mi < 4; ++mi) {
#pragma unroll
    for (int ni = 0; ni < 4; ++ni) {
      const int cl = wn * 64 + ni * 16 + lc;          // 0..127 within tile
      const float bb = bcat[n * COLS + cb + cl];
#pragma unroll
      for (int i = 0; i < 4; ++i) {
        const int tb = rb + wm * 64 + mi * 16 + lg4 + i;
        const size_t off = ((size_t)tb * 20 + n) * 256;
        const float val = acc[mi][ni][i] + bb;
        if (isQ) Qout[off + c0 + cl] = val;
        else dst16[off + c0 + cl] = f2bf(val);
      }
    }
  }
}

// ---------------- Kernel 2: attention per (t,b) ----------------
// grid 7680, block 192 (3 waves; 160 compute threads).
// K/V staged as f32 in LDS; h-stride 724 floats => 8 h-groups on distinct banks.
// Qf and out alias d_out (NO restrict): each thread reads only its own (h,n)
// 32-col segment and overwrites only that segment; every store depends on
// every q load via softmax, so ordering is enforced by dataflow.
constexpr int HS = 724;
__global__ __launch_bounds__(192) void attn_kernel(
    const float* Qf, const unsigned short* __restrict__ Kb,
    const unsigned short* __restrict__ Vb, float* out) {
  __shared__ float Ks[8 * HS];
  __shared__ float Vs[8 * HS];
  const int tb = blockIdx.x;
  const int tid = threadIdx.x;

  for (int c = tid; c < 1280; c += 192) {
    const int row = c >> 6;        // n: 0..19
    const int quad = c & 63;
    const int h = quad >> 3, f4 = (quad & 7) * 4;
    const size_t base = ((size_t)tb * 20 + row) * 256 + h * 32 + f4;
    const int didx = h * HS + row * 36 + f4;
    ushort4 uk = *(const ushort4*)&Kb[base];
    float4 fk;
    fk.x = bf2f(uk.x); fk.y = bf2f(uk.y); fk.z = bf2f(uk.z); fk.w = bf2f(uk.w);
    *(float4*)&Ks[didx] = fk;
    ushort4 uv = *(const ushort4*)&Vb[base];
    float4 fv;
    fv.x = bf2f(uv.x); fv.y = bf2f(uv.y); fv.z = bf2f(uv.z); fv.w = bf2f(uv.w);
    *(float4*)&Vs[didx] = fv;
  }
  __syncthreads();

  if (tid < 160) {
    const int h = tid / 20;
    const int nn = tid - h * 20;
    float q[32];
    const float* qp = &Qf[((size_t)tb * 20 + nn) * 256 + h * 32];
#pragma unroll
    for (int j = 0; j < 8; ++j) {
      float4 u = *(const float4*)&qp[j * 4];
      q[j * 4 + 0] = u.x; q[j * 4 + 1] = u.y;
      q[j * 4 + 2] = u.z; q[j * 4 + 3] = u.w;
    }
    float lg[20];
    float mx = -3.4e38f;
#pragma unroll
    for (int m = 0; m < 20; ++m) {
      float d = 0.f;
#pragma unroll
      for (int f = 0; f < 32; ++f) d = fmaf(q[f], Ks[h * HS + m * 36 + f], d);
      d *= SCALE;
      lg[m] = d;
      mx = fmaxf(mx, d);
    }
    float s = 0.f;
#pragma unroll
    for (int m = 0; m < 20; ++m) {
      float e = __expf(lg[m] - mx);
      lg[m] = e;
      s += e;
    }
    const float inv = 1.0f / s;
    float o[32] = {};
#pragma unroll
    for (int m = 0; m < 20; ++m) {
      const float p = lg[m] * inv;
#pragma unroll
      for (int f = 0; f < 32; ++f) o[f] = fmaf(p, Vs[h * HS + m * 36 + f], o[f]);
    }
    const size_t base = ((size_t)tb * 20 + nn) * 256 + h * 32;
#pragma unroll
    for (int f0 = 0; f0 < 32; f0 += 4) {
      float4 v4 = make_float4(o[f0], o[f0 + 1], o[f0 + 2], o[f0 + 3]);
      *(float4*)&out[base + f0] = v4;
    }
  }
}

extern "C" void kernel_launch(void* const* d_in, const int* in_sizes, int n_in,
                              void* d_out, int out_size, void* d_ws, size_t ws_size,
                              hipStream_t stream) {
  const float* inputs = (const float*)d_in[0];
  const float* Wk = (const float*)d_in[1];
  const float* bk = (const float*)d_in[2];
  const float* Wv = (const float*)d_in[3];
  const float* bv = (const float*)d_in[4];
  const float* Wq = (const float*)d_in[5];
  const float* bq = (const float*)d_in[6];
  float* out = (float*)d_out;

  const size_t seg = (size_t)MKV * 256 * sizeof(unsigned short);  // 78,643,200 B
  unsigned short* Kb = (unsigned short*)d_ws;
  unsigned short* Vb = (unsigned short*)((char*)d_ws + seg);
  unsigned short* Wcat = (unsigned short*)((char*)d_ws + 2 * seg);
  float* bcat = (float*)((char*)d_ws + 2 * seg + (size_t)20 * COLS * 256 * 2);

  prep<<<3900, 256, 0, stream>>>(Wk, bk, Wv, bv, Wq, bq, Wcat, bcat);
  fused_gemm<<<7200, 256, 0, stream>>>(inputs, Wcat, bcat, Kb, Vb, out);
  attn_kernel<<<TB_, 192, 0, stream>>>(out, Kb, Vb, out);
}